// Round 16
// baseline (215.122 us; speedup 1.0000x reference)
//
#include <hip/hip_runtime.h>

// B=2,S=2048,H=1024,NH=16,HD=64 fused attention block.
// R23 (session R14): R22 verified (attn 44.2us, conflicts 6.7M->557K, total
//   191.0). Residue analysis: GEMMs = ~134us for 34.4 GFLOP (~300 TF) = the
//   known reg-staged 2-barrier ceiling. This round: both GEMMs switch to
//   __builtin_amdgcn_global_load_lds width=16 staging (ladder step 3:
//   343->874 TF at this exact 128x128/BK=64 tile). LDS linear [128][64]
//   (dest must be wave-uniform + lane*16); frag reads take a 16-way bank
//   conflict (m98: benign at this structure). attn = R22 byte-identical.
// R15 resubmit: GPUAcquisitionTimeout (infra) — R23 never ran; byte-identical.
#define B_  2
#define S_  2048
#define H_  1024
#define NH_ 16
#define HD_ 64
#define M_  (B_*S_)   // 4096 rows

typedef __attribute__((ext_vector_type(8))) __bf16 bf16x8;
typedef __attribute__((ext_vector_type(4))) float  f32x4;
typedef __attribute__((ext_vector_type(8))) unsigned short us8;
typedef __attribute__((ext_vector_type(4))) float  fl4;

__device__ __forceinline__ unsigned short f2bf(float f) {
    unsigned int u = __float_as_uint(f);
    u += 0x7fffu + ((u >> 16) & 1u);          // round-to-nearest-even
    return (unsigned short)(u >> 16);
}

// ---------------- cast fp32 -> bf16 (x and the 4 weights) ----------------
__global__ __launch_bounds__(256) void cast_kernel(
    const float* __restrict__ x,
    const float* __restrict__ wq, const float* __restrict__ wk,
    const float* __restrict__ wv, const float* __restrict__ wo,
    unsigned short* __restrict__ xb, unsigned short* __restrict__ wb) {
    size_t t  = (size_t)blockIdx.x * 256 + threadIdx.x;
    size_t e0 = t * 4;
    const size_t XN = (size_t)M_ * H_;        // 4M
    const float* src;
    unsigned short* dst;
    if (e0 < XN) { src = x + e0; dst = xb + e0; }
    else {
        size_t j = e0 - XN;                    // 0..4M over 4 weights of 1M
        int w = (int)(j >> 20);
        size_t off = j & ((1u << 20) - 1);
        const float* wp = (w == 0) ? wq : (w == 1) ? wk : (w == 2) ? wv : wo;
        src = wp + off; dst = wb + j;
    }
    fl4 v = *(const fl4*)src;
    ushort4 o;
    o.x = f2bf(v.x); o.y = f2bf(v.y); o.z = f2bf(v.z); o.w = f2bf(v.w);
    *(ushort4*)dst = o;
}

// ------- QKV GEMM (128x128, 512 thr, global_load_lds staging) — R23 -------
// z==0 -> Q (pre-scaled by 1/8*log2e) ; z==1 -> K ; z==2 -> V transposed.
__global__ __launch_bounds__(512) void gemm_qkv(
    const unsigned short* __restrict__ xb, const unsigned short* __restrict__ wb,
    const float* __restrict__ bq, const float* __restrict__ bk,
    const float* __restrict__ bv,
    unsigned short* __restrict__ qb, unsigned short* __restrict__ kbuf,
    unsigned short* __restrict__ vT) {
    __shared__ __align__(16) unsigned short As[128 * 64];   // linear, no pad
    __shared__ __align__(16) unsigned short Bs[128 * 64];
    const int z = blockIdx.z;
    const unsigned short* W = wb + ((size_t)z << 20);
    const int m0 = blockIdx.x * 128, n0 = blockIdx.y * 128;
    const int t = threadIdx.x, lane = t & 63, w = t >> 6;   // w 0..7
    const int wm = w >> 2, wn = w & 3;                      // 2m x 4n
    const int quad = lane >> 4, l16 = lane & 15;
    // staging: wave w fills rows [w*8, w*8+8) (load0) and +64 (load1);
    // lane l -> row w*8 + l/8, col (l&7)*8  (16B per lane, contiguous LDS)
    const int srow = w * 8 + (lane >> 3);
    const int scol = (lane & 7) * 8;
    const unsigned short* gA0 = xb + (size_t)(m0 + srow) * H_ + scol;
    const unsigned short* gA1 = xb + (size_t)(m0 + 64 + srow) * H_ + scol;
    const unsigned short* gB0 = W  + (size_t)(n0 + srow) * H_ + scol;
    const unsigned short* gB1 = W  + (size_t)(n0 + 64 + srow) * H_ + scol;
    unsigned short* lA0 = &As[(w * 8) * 64];        // wave-uniform bases
    unsigned short* lA1 = &As[(64 + w * 8) * 64];
    unsigned short* lB0 = &Bs[(w * 8) * 64];
    unsigned short* lB1 = &Bs[(64 + w * 8) * 64];

    f32x4 acc[4][2] = {};
    for (int k0 = 0; k0 < H_; k0 += 64) {
        if (k0) __syncthreads();        // previous tile's readers done
        __builtin_amdgcn_global_load_lds((const unsigned int*)(gA0 + k0), (unsigned int*)lA0, 16, 0, 0);
        __builtin_amdgcn_global_load_lds((const unsigned int*)(gA1 + k0), (unsigned int*)lA1, 16, 0, 0);
        __builtin_amdgcn_global_load_lds((const unsigned int*)(gB0 + k0), (unsigned int*)lB0, 16, 0, 0);
        __builtin_amdgcn_global_load_lds((const unsigned int*)(gB1 + k0), (unsigned int*)lB1, 16, 0, 0);
        __syncthreads();                 // vmcnt(0) drained by barrier
#pragma unroll
        for (int kk = 0; kk < 64; kk += 32) {
            bf16x8 af[4], bfr[2];
#pragma unroll
            for (int i = 0; i < 4; i++)
                af[i]  = *(const bf16x8*)&As[(wm * 64 + i * 16 + l16) * 64 + kk + quad * 8];
#pragma unroll
            for (int jn = 0; jn < 2; jn++)
                bfr[jn] = *(const bf16x8*)&Bs[(wn * 32 + jn * 16 + l16) * 64 + kk + quad * 8];
#pragma unroll
            for (int mi = 0; mi < 4; mi++)
#pragma unroll
                for (int ni = 0; ni < 2; ni++)
                    acc[mi][ni] = __builtin_amdgcn_mfma_f32_16x16x32_bf16(
                        af[mi], bfr[ni], acc[mi][ni], 0, 0, 0);
        }
    }
    const float* bias = (z == 0) ? bq : (z == 1) ? bk : bv;
    if (z == 2) {
#pragma unroll
        for (int mi = 0; mi < 4; mi++) {
#pragma unroll
            for (int ni = 0; ni < 2; ni++) {
                int col  = n0 + wn * 32 + ni * 16 + l16;   // h*64+d
                float bval = bias[col];
                int row0 = m0 + wm * 64 + mi * 16 + quad * 4;  // b*2048+s
                int bb = row0 >> 11, s0 = row0 & 2047;
                ushort4 pk;
                pk.x = f2bf(acc[mi][ni][0] + bval);
                pk.y = f2bf(acc[mi][ni][1] + bval);
                pk.z = f2bf(acc[mi][ni][2] + bval);
                pk.w = f2bf(acc[mi][ni][3] + bval);
                *(ushort4*)&vT[((size_t)bb * NH_ * HD_ + col) * S_ + s0] = pk;
            }
        }
    } else {
        unsigned short* out = (z == 0) ? qb : kbuf;
        const float qs = (z == 0) ? 0.18033688f : 1.0f;   // (1/8)*log2(e) folded into Q
#pragma unroll
        for (int mi = 0; mi < 4; mi++) {
#pragma unroll
            for (int ni = 0; ni < 2; ni++) {
                int col = n0 + wn * 32 + ni * 16 + l16;
                float bval = bias[col];
#pragma unroll
                for (int r = 0; r < 4; r++) {
                    int row = m0 + wm * 64 + mi * 16 + quad * 4 + r;
                    out[(size_t)row * H_ + col] = f2bf((acc[mi][ni][r] + bval) * qs);
                }
            }
        }
    }
}

// ---- Wo GEMM + bias + residual (128x128, 512 thr, global_load_lds) -------
__global__ __launch_bounds__(512) void gemm_out(
    const unsigned short* __restrict__ ctxb, const unsigned short* __restrict__ wob,
    const float* __restrict__ bo, const float* __restrict__ x,
    float* __restrict__ y) {
    __shared__ __align__(16) unsigned short As[128 * 64];
    __shared__ __align__(16) unsigned short Bs[128 * 64];
    const int m0 = blockIdx.x * 128, n0 = blockIdx.y * 128;
    const int t = threadIdx.x, lane = t & 63, w = t >> 6;
    const int wm = w >> 2, wn = w & 3;
    const int quad = lane >> 4, l16 = lane & 15;
    const int srow = w * 8 + (lane >> 3);
    const int scol = (lane & 7) * 8;
    const unsigned short* gA0 = ctxb + (size_t)(m0 + srow) * H_ + scol;
    const unsigned short* gA1 = ctxb + (size_t)(m0 + 64 + srow) * H_ + scol;
    const unsigned short* gB0 = wob  + (size_t)(n0 + srow) * H_ + scol;
    const unsigned short* gB1 = wob  + (size_t)(n0 + 64 + srow) * H_ + scol;
    unsigned short* lA0 = &As[(w * 8) * 64];
    unsigned short* lA1 = &As[(64 + w * 8) * 64];
    unsigned short* lB0 = &Bs[(w * 8) * 64];
    unsigned short* lB1 = &Bs[(64 + w * 8) * 64];

    f32x4 acc[4][2] = {};
    for (int k0 = 0; k0 < H_; k0 += 64) {
        if (k0) __syncthreads();
        __builtin_amdgcn_global_load_lds((const unsigned int*)(gA0 + k0), (unsigned int*)lA0, 16, 0, 0);
        __builtin_amdgcn_global_load_lds((const unsigned int*)(gA1 + k0), (unsigned int*)lA1, 16, 0, 0);
        __builtin_amdgcn_global_load_lds((const unsigned int*)(gB0 + k0), (unsigned int*)lB0, 16, 0, 0);
        __builtin_amdgcn_global_load_lds((const unsigned int*)(gB1 + k0), (unsigned int*)lB1, 16, 0, 0);
        __syncthreads();
#pragma unroll
        for (int kk = 0; kk < 64; kk += 32) {
            bf16x8 af[4], bfr[2];
#pragma unroll
            for (int i = 0; i < 4; i++)
                af[i]  = *(const bf16x8*)&As[(wm * 64 + i * 16 + l16) * 64 + kk + quad * 8];
#pragma unroll
            for (int jn = 0; jn < 2; jn++)
                bfr[jn] = *(const bf16x8*)&Bs[(wn * 32 + jn * 16 + l16) * 64 + kk + quad * 8];
#pragma unroll
            for (int mi = 0; mi < 4; mi++)
#pragma unroll
                for (int ni = 0; ni < 2; ni++)
                    acc[mi][ni] = __builtin_amdgcn_mfma_f32_16x16x32_bf16(
                        af[mi], bfr[ni], acc[mi][ni], 0, 0, 0);
        }
    }
#pragma unroll
    for (int mi = 0; mi < 4; mi++) {
#pragma unroll
        for (int ni = 0; ni < 2; ni++) {
            int col = n0 + wn * 32 + ni * 16 + l16;
            float bval = bo[col];
#pragma unroll
            for (int r = 0; r < 4; r++) {
                size_t idx = (size_t)(m0 + wm * 64 + mi * 16 + quad * 4 + r) * H_ + col;
                y[idx] = acc[mi][ni][r] + bval + x[idx];
            }
        }
    }
}

// ---------------- Flash attention (causal), KVBLK=128, 2 blocks/CU ---------
// R22 verified (44.2us): grid 512 = 2 rounds x 32 bh x 8 slots; pads 68/132;
// chunked register-P strip. Byte-identical to R22.
__global__ __launch_bounds__(512, 4) void attn_kernel(
    const unsigned short* __restrict__ qb, const unsigned short* __restrict__ kb,
    const unsigned short* __restrict__ vT, unsigned short* __restrict__ ctxb) {
    __shared__ __align__(16) unsigned short Ks[2][128 * 68];   // [key][d] pad68
    __shared__ __align__(16) unsigned short Vt[2][64 * 132];   // [d][key] pad132
    __shared__ __align__(16) unsigned short Ps[128 * 44];      // [q-row][32key chunk] pad44
    const int flat = blockIdx.x;                  // 0..511
    const int rnd  = flat >> 8;                   // 0 or 1
    const int within = flat & 255;
    const int xcd = within & 7, s2 = within >> 3; // s2 0..31
    const int bh  = xcd * 4 + (s2 >> 3);          // 8 blocks of a bh per XCD/round
    const int j   = s2 & 7;
    const int fj  = (j & 1) ? (15 - j) : j;
    const int p2  = rnd ? (15 - fj) : fj;         // tile index 0..15
    const int b = bh >> 4, h = bh & 15;
    const int t = threadIdx.x, lane = t & 63, wid = t >> 6;   // wid 0..7
    const int quad = lane >> 4, l16 = lane & 15;
    const int skr = t >> 2, skc = (t & 3) * 16;   // K staging: 128r x 64c
    const int svr = t >> 3, svc = (t & 7) * 16;   // V staging: 64r x 128c
    const size_t headoff = (size_t)h * HD_;
    const unsigned short* vtb = vT + ((size_t)(b * NH_ + h) * HD_) * S_;  // [d][s]
    const int qrow = wid * 16 + l16;              // row within tile, 0..127

    const int q0 = p2 * 128;
    const int nsteps = p2 + 1;                    // 128 keys per step

    const size_t qr = (size_t)(b * S_ + q0 + qrow);
    bf16x8 qva = *(const bf16x8*)(qb + qr * H_ + headoff + quad * 8);
    bf16x8 qvb = *(const bf16x8*)(qb + qr * H_ + headoff + 32 + quad * 8);

    float m1 = -1e30f, l1 = 0.f;
    f32x4 o1[4] = {};

    const unsigned short* kptr = kb  + (size_t)(b * S_ + skr) * H_ + headoff + skc;
    const unsigned short* vptr = vtb + (size_t)svr * S_ + svc;
    us8 nk0 = *(const us8*)kptr,  nk1 = *(const us8*)(kptr + 8);
    us8 nv0 = *(const us8*)vptr,  nv1 = *(const us8*)(vptr + 8);
    *(us8*)&Ks[0][skr * 68 + skc]      = nk0;
    *(us8*)&Ks[0][skr * 68 + skc + 8]  = nk1;
    *(us8*)&Vt[0][svr * 132 + svc]     = nv0;
    *(us8*)&Vt[0][svr * 132 + svc + 8] = nv1;
    __syncthreads();

    for (int s = 0; s < nsteps; s++) {
        const int buf = s & 1;
        const bool pf = (s + 1 < nsteps);
        if (pf) {
            kptr += (size_t)128 * H_;
            vptr += 128;
            nk0 = *(const us8*)kptr;  nk1 = *(const us8*)(kptr + 8);
            nv0 = *(const us8*)vptr;  nv1 = *(const us8*)(vptr + 8);
        }
        f32x4 sacc[8] = {};
        __builtin_amdgcn_s_setprio(1);
#pragma unroll
        for (int kk = 0; kk < 64; kk += 32) {
            bf16x8 bqf = (kk == 0) ? qva : qvb;
#pragma unroll
            for (int nt = 0; nt < 8; nt++) {
                bf16x8 ak = *(const bf16x8*)&Ks[buf][(nt * 16 + l16) * 68 + kk + quad * 8];
                sacc[nt] = __builtin_amdgcn_mfma_f32_16x16x32_bf16(ak, bqf, sacc[nt], 0, 0, 0);
            }
        }
        __builtin_amdgcn_s_setprio(0);
        if (s == p2) {                            // final step: diagonal mask
#pragma unroll
            for (int nt = 0; nt < 8; nt++) {
#pragma unroll
                for (int r = 0; r < 4; r++) {
                    int key = nt * 16 + quad * 4 + r;
                    if (key > qrow) sacc[nt][r] = -1e30f;
                }
            }
        }
        // tree max-reduce then cross-quad combine
        float tm[8];
#pragma unroll
        for (int nt = 0; nt < 8; nt++)
            tm[nt] = fmaxf(fmaxf(sacc[nt][0], sacc[nt][1]), fmaxf(sacc[nt][2], sacc[nt][3]));
        float mx = fmaxf(fmaxf(fmaxf(tm[0], tm[1]), fmaxf(tm[2], tm[3])),
                         fmaxf(fmaxf(tm[4], tm[5]), fmaxf(tm[6], tm[7])));
        mx = fmaxf(mx, __shfl_xor(mx, 16));
        mx = fmaxf(mx, __shfl_xor(mx, 32));
        // defer-rescale: skip alpha exp + O-rescale while max growth <= 5
        const bool skip = __all(mx <= m1 + 5.0f);
        float m_new = skip ? m1 : fmaxf(m1, mx);
        float ss = 0.f;
        ushort4 pks[8];                           // packed P kept in registers
#pragma unroll
        for (int nt = 0; nt < 8; nt++) {
            float p0 = __builtin_amdgcn_exp2f(sacc[nt][0] - m_new);
            float p1 = __builtin_amdgcn_exp2f(sacc[nt][1] - m_new);
            float p2e = __builtin_amdgcn_exp2f(sacc[nt][2] - m_new);
            float p3 = __builtin_amdgcn_exp2f(sacc[nt][3] - m_new);
            ss += (p0 + p1) + (p2e + p3);
            pks[nt].x = (unsigned short)(__float_as_uint(p0) >> 16);
            pks[nt].y = (unsigned short)(__float_as_uint(p1) >> 16);
            pks[nt].z = (unsigned short)(__float_as_uint(p2e) >> 16);
            pks[nt].w = (unsigned short)(__float_as_uint(p3) >> 16);
        }
        ss += __shfl_xor(ss, 16);
        ss += __shfl_xor(ss, 32);
        if (skip) {
            l1 += ss;
        } else {
            float alpha = __builtin_amdgcn_exp2f(m1 - m_new);
            l1 = l1 * alpha + ss;
            m1 = m_new;
#pragma unroll
            for (int dt = 0; dt < 4; dt++)
#pragma unroll
                for (int r = 0; r < 4; r++) o1[dt][r] *= alpha;
        }
        // PV: chunked wave-private Ps strip (32 keys at a time). Same-wave
        // in-order DS pipe + lgkmcnt ordering -> no barrier needed.
        __builtin_amdgcn_s_setprio(1);
#pragma unroll
        for (int kk = 0; kk < 128; kk += 32) {
            const int nb = kk >> 4;               // 0,2,4,6
            *(ushort4*)&Ps[(wid * 16 + l16) * 44 + quad * 4]      = pks[nb];
            *(ushort4*)&Ps[(wid * 16 + l16) * 44 + 16 + quad * 4] = pks[nb + 1];
            bf16x8 pfr = *(const bf16x8*)&Ps[(wid * 16 + l16) * 44 + quad * 8];
#pragma unroll
            for (int dt = 0; dt < 4; dt++) {
                bf16x8 vf = *(const bf16x8*)&Vt[buf][(dt * 16 + l16) * 132 + kk + quad * 8];
                o1[dt] = __builtin_amdgcn_mfma_f32_16x16x32_bf16(vf, pfr, o1[dt], 0, 0, 0);
            }
        }
        __builtin_amdgcn_s_setprio(0);
        if (pf) {
            *(us8*)&Ks[buf ^ 1][skr * 68 + skc]      = nk0;
            *(us8*)&Ks[buf ^ 1][skr * 68 + skc + 8]  = nk1;
            *(us8*)&Vt[buf ^ 1][svr * 132 + svc]     = nv0;
            *(us8*)&Vt[buf ^ 1][svr * 132 + svc + 8] = nv1;
            __syncthreads();
        }
    }
    {
        const float inv = 1.0f / l1;
        size_t row = (size_t)(b * S_ + q0 + qrow);
#pragma unroll
        for (int dt = 0; dt < 4; dt++) {
            ushort4 pk;
            pk.x = f2bf(o1[dt][0] * inv);
            pk.y = f2bf(o1[dt][1] * inv);
            pk.z = f2bf(o1[dt][2] * inv);
            pk.w = f2bf(o1[dt][3] * inv);
            *(ushort4*)&ctxb[row * H_ + headoff + dt * 16 + quad * 4] = pk;
        }
    }
}

// ---------------- LayerNorm (1 block per row) ----------------
__global__ __launch_bounds__(256) void ln_kernel(
    const float* __restrict__ y, const float* __restrict__ g,
    const float* __restrict__ bta, float* __restrict__ out) {
    __shared__ float red[8];
    const int row = blockIdx.x, t = threadIdx.x;
    fl4 v = *(const fl4*)(y + (size_t)row * H_ + t * 4);
    float s  = v.x + v.y + v.z + v.w;
    float sq = v.x * v.x + v.y * v.y + v.z * v.z + v.w * v.w;
    for (int m = 1; m < 64; m <<= 1) { s += __shfl_xor(s, m); sq += __shfl_xor(sq, m); }
    const int wid = t >> 6, lane = t & 63;
    if (lane == 0) { red[wid * 2] = s; red[wid * 2 + 1] = sq; }
    __syncthreads();
    s  = red[0] + red[2] + red[4] + red[6];
    sq = red[1] + red[3] + red[5] + red[7];
    float mu   = s * (1.0f / H_);
    float var  = sq * (1.0f / H_) - mu * mu;
    float rstd = rsqrtf(fmaxf(var, 0.f) + 1e-12f);
    fl4 gg = *(const fl4*)(g + t * 4);
    fl4 bb = *(const fl4*)(bta + t * 4);
    fl4 o;
    o.x = (v.x - mu) * rstd * gg.x + bb.x;
    o.y = (v.y - mu) * rstd * gg.y + bb.y;
    o.z = (v.z - mu) * rstd * gg.z + bb.z;
    o.w = (v.w - mu) * rstd * gg.w + bb.w;
    *(fl4*)(out + (size_t)row * H_ + t * 4) = o;
}

extern "C" void kernel_launch(void* const* d_in, const int* in_sizes, int n_in,
                              void* d_out, int out_size, void* d_ws, size_t ws_size,
                              hipStream_t stream) {
    const float* x  = (const float*)d_in[0];
    const float* Wq = (const float*)d_in[1];
    const float* bq = (const float*)d_in[2];
    const float* Wk = (const float*)d_in[3];
    const float* bk = (const float*)d_in[4];
    const float* Wv = (const float*)d_in[5];
    const float* bv = (const float*)d_in[6];
    const float* Wo = (const float*)d_in[7];
    const float* bo = (const float*)d_in[8];
    const float* lg = (const float*)d_in[9];
    const float* lb = (const float*)d_in[10];
    float* out = (float*)d_out;

    const size_t MEG = 1024u * 1024u;
    unsigned short* ws16 = (unsigned short*)d_ws;
    unsigned short* xb   = ws16;                  // 4M bf16
    unsigned short* wb   = ws16 + 4 * MEG;        // 4x1M bf16 (Wq,Wk,Wv,Wo)
    unsigned short* qb   = ws16 + 8 * MEG;
    unsigned short* kb   = ws16 + 12 * MEG;
    unsigned short* vT   = ws16 + 16 * MEG;       // transposed V [b,h,d,s]
    unsigned short* ctxb = ws16 + 20 * MEG;
    float* y = (float*)(ws16 + 24 * MEG);         // 4M fp32; total 64 MB

    cast_kernel<<<8192, 256, 0, stream>>>(x, Wq, Wk, Wv, Wo, xb, wb);
    gemm_qkv<<<dim3(32, 8, 3), 512, 0, stream>>>(xb, wb, bq, bk, bv, qb, kb, vT);
    attn_kernel<<<dim3(512), 512, 0, stream>>>(qb, kb, vT, ctxb);
    gemm_out<<<dim3(32, 8), 512, 0, stream>>>(ctxb, wb + 3 * MEG, bo, x, y);
    ln_kernel<<<4096, 256, 0, stream>>>(y, lg, lb, out);
}

// Round 18
// 189.771 us; speedup vs baseline: 1.1336x; 1.1336x over previous
//
#include <hip/hip_runtime.h>

// B=2,S=2048,H=1024,NH=16,HD=64 fused attention block.
// R24 (session R16): R23's global_load_lds GEMM REGRESSED (gemm_qkv 55.6us
//   = 464 TF, VALUBusy 10.6% -> exposed per-step load latency + 14M LDS
//   conflicts; total 215.1). Key learning: the reg-staged R11 GEMM was
//   already <44us (>=586 TF, never in R22 top-5) — m97's 874 TF recipe does
//   not transfer to K=N=1024 (m102 N-curve). REVERT to the R22-verified
//   config (191.0us): reg-staged GEMMs (pad 72), attn KVBLK=128 2-blk/CU
//   (pads 68/132, chunked register-P), cast, LN. Byte-identical to R22.
// R17 resubmit: GPUAcquisitionTimeout (infra) — banking the verified state.
#define B_  2
#define S_  2048
#define H_  1024
#define NH_ 16
#define HD_ 64
#define M_  (B_*S_)   // 4096 rows

typedef __attribute__((ext_vector_type(8))) __bf16 bf16x8;
typedef __attribute__((ext_vector_type(4))) float  f32x4;
typedef __attribute__((ext_vector_type(8))) unsigned short us8;
typedef __attribute__((ext_vector_type(4))) float  fl4;

__device__ __forceinline__ unsigned short f2bf(float f) {
    unsigned int u = __float_as_uint(f);
    u += 0x7fffu + ((u >> 16) & 1u);          // round-to-nearest-even
    return (unsigned short)(u >> 16);
}

// ---------------- cast fp32 -> bf16 (x and the 4 weights) ----------------
__global__ __launch_bounds__(256) void cast_kernel(
    const float* __restrict__ x,
    const float* __restrict__ wq, const float* __restrict__ wk,
    const float* __restrict__ wv, const float* __restrict__ wo,
    unsigned short* __restrict__ xb, unsigned short* __restrict__ wb) {
    size_t t  = (size_t)blockIdx.x * 256 + threadIdx.x;
    size_t e0 = t * 4;
    const size_t XN = (size_t)M_ * H_;        // 4M
    const float* src;
    unsigned short* dst;
    if (e0 < XN) { src = x + e0; dst = xb + e0; }
    else {
        size_t j = e0 - XN;                    // 0..4M over 4 weights of 1M
        int w = (int)(j >> 20);
        size_t off = j & ((1u << 20) - 1);
        const float* wp = (w == 0) ? wq : (w == 1) ? wk : (w == 2) ? wv : wo;
        src = wp + off; dst = wb + j;
    }
    fl4 v = *(const fl4*)src;
    ushort4 o;
    o.x = f2bf(v.x); o.y = f2bf(v.y); o.z = f2bf(v.z); o.w = f2bf(v.w);
    *(ushort4*)dst = o;
}

// ---------------- QKV GEMM (128x128, 512 thr, reg-prefetch) — R11 ----------
// z==0 -> Q (pre-scaled by 1/8*log2e) ; z==1 -> K ; z==2 -> V transposed.
__global__ __launch_bounds__(512) void gemm_qkv(
    const unsigned short* __restrict__ xb, const unsigned short* __restrict__ wb,
    const float* __restrict__ bq, const float* __restrict__ bk,
    const float* __restrict__ bv,
    unsigned short* __restrict__ qb, unsigned short* __restrict__ kbuf,
    unsigned short* __restrict__ vT) {
    __shared__ __align__(16) unsigned short As[128 * 72];
    __shared__ __align__(16) unsigned short Bs[128 * 72];
    const int z = blockIdx.z;
    const unsigned short* W = wb + ((size_t)z << 20);
    const int m0 = blockIdx.x * 128, n0 = blockIdx.y * 128;
    const int t = threadIdx.x, lane = t & 63, w = t >> 6;   // w 0..7
    const int wm = w >> 2, wn = w & 3;                      // 2m x 4n
    const int quad = lane >> 4, l16 = lane & 15;
    const int sr = t >> 2, sc = (t & 3) * 16;               // staging row/col
    const unsigned short* ga = xb + (size_t)(m0 + sr) * H_ + sc;
    const unsigned short* gb = W  + (size_t)(n0 + sr) * H_ + sc;

    us8 a0 = *(const us8*)(ga),     a1 = *(const us8*)(ga + 8);
    us8 b0 = *(const us8*)(gb),     b1 = *(const us8*)(gb + 8);

    f32x4 acc[4][2] = {};
    for (int k0 = 0; k0 < H_; k0 += 64) {
        if (k0) __syncthreads();        // LDS readers of previous kstep done
        *(us8*)&As[sr * 72 + sc]     = a0;  *(us8*)&As[sr * 72 + sc + 8] = a1;
        *(us8*)&Bs[sr * 72 + sc]     = b0;  *(us8*)&Bs[sr * 72 + sc + 8] = b1;
        __syncthreads();                 // tile published
        if (k0 + 64 < H_) {              // prefetch next tile (flies under MFMA)
            ga += 64; gb += 64;
            a0 = *(const us8*)(ga);  a1 = *(const us8*)(ga + 8);
            b0 = *(const us8*)(gb);  b1 = *(const us8*)(gb + 8);
        }
#pragma unroll
        for (int kk = 0; kk < 64; kk += 32) {
            bf16x8 af[4], bfr[2];
#pragma unroll
            for (int i = 0; i < 4; i++)
                af[i]  = *(const bf16x8*)&As[(wm * 64 + i * 16 + l16) * 72 + kk + quad * 8];
#pragma unroll
            for (int jn = 0; jn < 2; jn++)
                bfr[jn] = *(const bf16x8*)&Bs[(wn * 32 + jn * 16 + l16) * 72 + kk + quad * 8];
#pragma unroll
            for (int mi = 0; mi < 4; mi++)
#pragma unroll
                for (int ni = 0; ni < 2; ni++)
                    acc[mi][ni] = __builtin_amdgcn_mfma_f32_16x16x32_bf16(
                        af[mi], bfr[ni], acc[mi][ni], 0, 0, 0);
        }
    }
    const float* bias = (z == 0) ? bq : (z == 1) ? bk : bv;
    if (z == 2) {
#pragma unroll
        for (int mi = 0; mi < 4; mi++) {
#pragma unroll
            for (int ni = 0; ni < 2; ni++) {
                int col  = n0 + wn * 32 + ni * 16 + l16;   // h*64+d
                float bval = bias[col];
                int row0 = m0 + wm * 64 + mi * 16 + quad * 4;  // b*2048+s
                int bb = row0 >> 11, s0 = row0 & 2047;
                ushort4 pk;
                pk.x = f2bf(acc[mi][ni][0] + bval);
                pk.y = f2bf(acc[mi][ni][1] + bval);
                pk.z = f2bf(acc[mi][ni][2] + bval);
                pk.w = f2bf(acc[mi][ni][3] + bval);
                *(ushort4*)&vT[((size_t)bb * NH_ * HD_ + col) * S_ + s0] = pk;
            }
        }
    } else {
        unsigned short* out = (z == 0) ? qb : kbuf;
        const float qs = (z == 0) ? 0.18033688f : 1.0f;   // (1/8)*log2(e) folded into Q
#pragma unroll
        for (int mi = 0; mi < 4; mi++) {
#pragma unroll
            for (int ni = 0; ni < 2; ni++) {
                int col = n0 + wn * 32 + ni * 16 + l16;
                float bval = bias[col];
#pragma unroll
                for (int r = 0; r < 4; r++) {
                    int row = m0 + wm * 64 + mi * 16 + quad * 4 + r;
                    out[(size_t)row * H_ + col] = f2bf((acc[mi][ni][r] + bval) * qs);
                }
            }
        }
    }
}

// ---------------- Wo GEMM + bias + residual (128x128, 512 thr) — R11 -------
__global__ __launch_bounds__(512) void gemm_out(
    const unsigned short* __restrict__ ctxb, const unsigned short* __restrict__ wob,
    const float* __restrict__ bo, const float* __restrict__ x,
    float* __restrict__ y) {
    __shared__ __align__(16) unsigned short As[128 * 72];
    __shared__ __align__(16) unsigned short Bs[128 * 72];
    const int m0 = blockIdx.x * 128, n0 = blockIdx.y * 128;
    const int t = threadIdx.x, lane = t & 63, w = t >> 6;
    const int wm = w >> 2, wn = w & 3;
    const int quad = lane >> 4, l16 = lane & 15;
    const int sr = t >> 2, sc = (t & 3) * 16;
    const unsigned short* ga = ctxb + (size_t)(m0 + sr) * H_ + sc;
    const unsigned short* gb = wob  + (size_t)(n0 + sr) * H_ + sc;

    us8 a0 = *(const us8*)(ga),     a1 = *(const us8*)(ga + 8);
    us8 b0 = *(const us8*)(gb),     b1 = *(const us8*)(gb + 8);

    f32x4 acc[4][2] = {};
    for (int k0 = 0; k0 < H_; k0 += 64) {
        if (k0) __syncthreads();
        *(us8*)&As[sr * 72 + sc]     = a0;  *(us8*)&As[sr * 72 + sc + 8] = a1;
        *(us8*)&Bs[sr * 72 + sc]     = b0;  *(us8*)&Bs[sr * 72 + sc + 8] = b1;
        __syncthreads();
        if (k0 + 64 < H_) {
            ga += 64; gb += 64;
            a0 = *(const us8*)(ga);  a1 = *(const us8*)(ga + 8);
            b0 = *(const us8*)(gb);  b1 = *(const us8*)(gb + 8);
        }
#pragma unroll
        for (int kk = 0; kk < 64; kk += 32) {
            bf16x8 af[4], bfr[2];
#pragma unroll
            for (int i = 0; i < 4; i++)
                af[i]  = *(const bf16x8*)&As[(wm * 64 + i * 16 + l16) * 72 + kk + quad * 8];
#pragma unroll
            for (int jn = 0; jn < 2; jn++)
                bfr[jn] = *(const bf16x8*)&Bs[(wn * 32 + jn * 16 + l16) * 72 + kk + quad * 8];
#pragma unroll
            for (int mi = 0; mi < 4; mi++)
#pragma unroll
                for (int ni = 0; ni < 2; ni++)
                    acc[mi][ni] = __builtin_amdgcn_mfma_f32_16x16x32_bf16(
                        af[mi], bfr[ni], acc[mi][ni], 0, 0, 0);
        }
    }
#pragma unroll
    for (int mi = 0; mi < 4; mi++) {
#pragma unroll
        for (int ni = 0; ni < 2; ni++) {
            int col = n0 + wn * 32 + ni * 16 + l16;
            float bval = bo[col];
#pragma unroll
            for (int r = 0; r < 4; r++) {
                size_t idx = (size_t)(m0 + wm * 64 + mi * 16 + quad * 4 + r) * H_ + col;
                y[idx] = acc[mi][ni][r] + bval + x[idx];
            }
        }
    }
}

// ---------------- Flash attention (causal), KVBLK=128, 2 blocks/CU ---------
// R22 verified (44.2us): grid 512 = 2 rounds x 32 bh x 8 slots; pads 68/132;
// chunked register-P strip. Byte-identical to R22.
__global__ __launch_bounds__(512, 4) void attn_kernel(
    const unsigned short* __restrict__ qb, const unsigned short* __restrict__ kb,
    const unsigned short* __restrict__ vT, unsigned short* __restrict__ ctxb) {
    __shared__ __align__(16) unsigned short Ks[2][128 * 68];   // [key][d] pad68
    __shared__ __align__(16) unsigned short Vt[2][64 * 132];   // [d][key] pad132
    __shared__ __align__(16) unsigned short Ps[128 * 44];      // [q-row][32key chunk] pad44
    const int flat = blockIdx.x;                  // 0..511
    const int rnd  = flat >> 8;                   // 0 or 1
    const int within = flat & 255;
    const int xcd = within & 7, s2 = within >> 3; // s2 0..31
    const int bh  = xcd * 4 + (s2 >> 3);          // 8 blocks of a bh per XCD/round
    const int j   = s2 & 7;
    const int fj  = (j & 1) ? (15 - j) : j;
    const int p2  = rnd ? (15 - fj) : fj;         // tile index 0..15
    const int b = bh >> 4, h = bh & 15;
    const int t = threadIdx.x, lane = t & 63, wid = t >> 6;   // wid 0..7
    const int quad = lane >> 4, l16 = lane & 15;
    const int skr = t >> 2, skc = (t & 3) * 16;   // K staging: 128r x 64c
    const int svr = t >> 3, svc = (t & 7) * 16;   // V staging: 64r x 128c
    const size_t headoff = (size_t)h * HD_;
    const unsigned short* vtb = vT + ((size_t)(b * NH_ + h) * HD_) * S_;  // [d][s]
    const int qrow = wid * 16 + l16;              // row within tile, 0..127

    const int q0 = p2 * 128;
    const int nsteps = p2 + 1;                    // 128 keys per step

    const size_t qr = (size_t)(b * S_ + q0 + qrow);
    bf16x8 qva = *(const bf16x8*)(qb + qr * H_ + headoff + quad * 8);
    bf16x8 qvb = *(const bf16x8*)(qb + qr * H_ + headoff + 32 + quad * 8);

    float m1 = -1e30f, l1 = 0.f;
    f32x4 o1[4] = {};

    const unsigned short* kptr = kb  + (size_t)(b * S_ + skr) * H_ + headoff + skc;
    const unsigned short* vptr = vtb + (size_t)svr * S_ + svc;
    us8 nk0 = *(const us8*)kptr,  nk1 = *(const us8*)(kptr + 8);
    us8 nv0 = *(const us8*)vptr,  nv1 = *(const us8*)(vptr + 8);
    *(us8*)&Ks[0][skr * 68 + skc]      = nk0;
    *(us8*)&Ks[0][skr * 68 + skc + 8]  = nk1;
    *(us8*)&Vt[0][svr * 132 + svc]     = nv0;
    *(us8*)&Vt[0][svr * 132 + svc + 8] = nv1;
    __syncthreads();

    for (int s = 0; s < nsteps; s++) {
        const int buf = s & 1;
        const bool pf = (s + 1 < nsteps);
        if (pf) {
            kptr += (size_t)128 * H_;
            vptr += 128;
            nk0 = *(const us8*)kptr;  nk1 = *(const us8*)(kptr + 8);
            nv0 = *(const us8*)vptr;  nv1 = *(const us8*)(vptr + 8);
        }
        f32x4 sacc[8] = {};
        __builtin_amdgcn_s_setprio(1);
#pragma unroll
        for (int kk = 0; kk < 64; kk += 32) {
            bf16x8 bqf = (kk == 0) ? qva : qvb;
#pragma unroll
            for (int nt = 0; nt < 8; nt++) {
                bf16x8 ak = *(const bf16x8*)&Ks[buf][(nt * 16 + l16) * 68 + kk + quad * 8];
                sacc[nt] = __builtin_amdgcn_mfma_f32_16x16x32_bf16(ak, bqf, sacc[nt], 0, 0, 0);
            }
        }
        __builtin_amdgcn_s_setprio(0);
        if (s == p2) {                            // final step: diagonal mask
#pragma unroll
            for (int nt = 0; nt < 8; nt++) {
#pragma unroll
                for (int r = 0; r < 4; r++) {
                    int key = nt * 16 + quad * 4 + r;
                    if (key > qrow) sacc[nt][r] = -1e30f;
                }
            }
        }
        // tree max-reduce then cross-quad combine
        float tm[8];
#pragma unroll
        for (int nt = 0; nt < 8; nt++)
            tm[nt] = fmaxf(fmaxf(sacc[nt][0], sacc[nt][1]), fmaxf(sacc[nt][2], sacc[nt][3]));
        float mx = fmaxf(fmaxf(fmaxf(tm[0], tm[1]), fmaxf(tm[2], tm[3])),
                         fmaxf(fmaxf(tm[4], tm[5]), fmaxf(tm[6], tm[7])));
        mx = fmaxf(mx, __shfl_xor(mx, 16));
        mx = fmaxf(mx, __shfl_xor(mx, 32));
        // defer-rescale: skip alpha exp + O-rescale while max growth <= 5
        const bool skip = __all(mx <= m1 + 5.0f);
        float m_new = skip ? m1 : fmaxf(m1, mx);
        float ss = 0.f;
        ushort4 pks[8];                           // packed P kept in registers
#pragma unroll
        for (int nt = 0; nt < 8; nt++) {
            float p0 = __builtin_amdgcn_exp2f(sacc[nt][0] - m_new);
            float p1 = __builtin_amdgcn_exp2f(sacc[nt][1] - m_new);
            float p2e = __builtin_amdgcn_exp2f(sacc[nt][2] - m_new);
            float p3 = __builtin_amdgcn_exp2f(sacc[nt][3] - m_new);
            ss += (p0 + p1) + (p2e + p3);
            pks[nt].x = (unsigned short)(__float_as_uint(p0) >> 16);
            pks[nt].y = (unsigned short)(__float_as_uint(p1) >> 16);
            pks[nt].z = (unsigned short)(__float_as_uint(p2e) >> 16);
            pks[nt].w = (unsigned short)(__float_as_uint(p3) >> 16);
        }
        ss += __shfl_xor(ss, 16);
        ss += __shfl_xor(ss, 32);
        if (skip) {
            l1 += ss;
        } else {
            float alpha = __builtin_amdgcn_exp2f(m1 - m_new);
            l1 = l1 * alpha + ss;
            m1 = m_new;
#pragma unroll
            for (int dt = 0; dt < 4; dt++)
#pragma unroll
                for (int r = 0; r < 4; r++) o1[dt][r] *= alpha;
        }
        // PV: chunked wave-private Ps strip (32 keys at a time). Same-wave
        // in-order DS pipe + lgkmcnt ordering -> no barrier needed.
        __builtin_amdgcn_s_setprio(1);
#pragma unroll
        for (int kk = 0; kk < 128; kk += 32) {
            const int nb = kk >> 4;               // 0,2,4,6
            *(ushort4*)&Ps[(wid * 16 + l16) * 44 + quad * 4]      = pks[nb];
            *(ushort4*)&Ps[(wid * 16 + l16) * 44 + 16 + quad * 4] = pks[nb + 1];
            bf16x8 pfr = *(const bf16x8*)&Ps[(wid * 16 + l16) * 44 + quad * 8];
#pragma unroll
            for (int dt = 0; dt < 4; dt++) {
                bf16x8 vf = *(const bf16x8*)&Vt[buf][(dt * 16 + l16) * 132 + kk + quad * 8];
                o1[dt] = __builtin_amdgcn_mfma_f32_16x16x32_bf16(vf, pfr, o1[dt], 0, 0, 0);
            }
        }
        __builtin_amdgcn_s_setprio(0);
        if (pf) {
            *(us8*)&Ks[buf ^ 1][skr * 68 + skc]      = nk0;
            *(us8*)&Ks[buf ^ 1][skr * 68 + skc + 8]  = nk1;
            *(us8*)&Vt[buf ^ 1][svr * 132 + svc]     = nv0;
            *(us8*)&Vt[buf ^ 1][svr * 132 + svc + 8] = nv1;
            __syncthreads();
        }
    }
    {
        const float inv = 1.0f / l1;
        size_t row = (size_t)(b * S_ + q0 + qrow);
#pragma unroll
        for (int dt = 0; dt < 4; dt++) {
            ushort4 pk;
            pk.x = f2bf(o1[dt][0] * inv);
            pk.y = f2bf(o1[dt][1] * inv);
            pk.z = f2bf(o1[dt][2] * inv);
            pk.w = f2bf(o1[dt][3] * inv);
            *(ushort4*)&ctxb[row * H_ + headoff + dt * 16 + quad * 4] = pk;
        }
    }
}

// ---------------- LayerNorm (1 block per row) ----------------
__global__ __launch_bounds__(256) void ln_kernel(
    const float* __restrict__ y, const float* __restrict__ g,
    const float* __restrict__ bta, float* __restrict__ out) {
    __shared__ float red[8];
    const int row = blockIdx.x, t = threadIdx.x;
    fl4 v = *(const fl4*)(y + (size_t)row * H_ + t * 4);
    float s  = v.x + v.y + v.z + v.w;
    float sq = v.x * v.x + v.y * v.y + v.z * v.z + v.w * v.w;
    for (int m = 1; m < 64; m <<= 1) { s += __shfl_xor(s, m); sq += __shfl_xor(sq, m); }
    const int wid = t >> 6, lane = t & 63;
    if (lane == 0) { red[wid * 2] = s; red[wid * 2 + 1] = sq; }
    __syncthreads();
    s  = red[0] + red[2] + red[4] + red[6];
    sq = red[1] + red[3] + red[5] + red[7];
    float mu   = s * (1.0f / H_);
    float var  = sq * (1.0f / H_) - mu * mu;
    float rstd = rsqrtf(fmaxf(var, 0.f) + 1e-12f);
    fl4 gg = *(const fl4*)(g + t * 4);
    fl4 bb = *(const fl4*)(bta + t * 4);
    fl4 o;
    o.x = (v.x - mu) * rstd * gg.x + bb.x;
    o.y = (v.y - mu) * rstd * gg.y + bb.y;
    o.z = (v.z - mu) * rstd * gg.z + bb.z;
    o.w = (v.w - mu) * rstd * gg.w + bb.w;
    *(fl4*)(out + (size_t)row * H_ + t * 4) = o;
}

extern "C" void kernel_launch(void* const* d_in, const int* in_sizes, int n_in,
                              void* d_out, int out_size, void* d_ws, size_t ws_size,
                              hipStream_t stream) {
    const float* x  = (const float*)d_in[0];
    const float* Wq = (const float*)d_in[1];
    const float* bq = (const float*)d_in[2];
    const float* Wk = (const float*)d_in[3];
    const float* bk = (const float*)d_in[4];
    const float* Wv = (const float*)d_in[5];
    const float* bv = (const float*)d_in[6];
    const float* Wo = (const float*)d_in[7];
    const float* bo = (const float*)d_in[8];
    const float* lg = (const float*)d_in[9];
    const float* lb = (const float*)d_in[10];
    float* out = (float*)d_out;

    const size_t MEG = 1024u * 1024u;
    unsigned short* ws16 = (unsigned short*)d_ws;
    unsigned short* xb   = ws16;                  // 4M bf16
    unsigned short* wb   = ws16 + 4 * MEG;        // 4x1M bf16 (Wq,Wk,Wv,Wo)
    unsigned short* qb   = ws16 + 8 * MEG;
    unsigned short* kb   = ws16 + 12 * MEG;
    unsigned short* vT   = ws16 + 16 * MEG;       // transposed V [b,h,d,s]
    unsigned short* ctxb = ws16 + 20 * MEG;
    float* y = (float*)(ws16 + 24 * MEG);         // 4M fp32; total 64 MB

    cast_kernel<<<8192, 256, 0, stream>>>(x, Wq, Wk, Wv, Wo, xb, wb);
    gemm_qkv<<<dim3(32, 8, 3), 512, 0, stream>>>(xb, wb, bq, bk, bv, qb, kb, vT);
    attn_kernel<<<dim3(512), 512, 0, stream>>>(qb, kb, vT, ctxb);
    gemm_out<<<dim3(32, 8), 512, 0, stream>>>(ctxb, wb + 3 * MEG, bo, x, y);
    ln_kernel<<<4096, 256, 0, stream>>>(y, lg, lb, out);
}